// Round 1
// baseline (3478.830 us; speedup 1.0000x reference)
//
#include <hip/hip_runtime.h>

// SNN: 3-layer LIF MLP, T=10 steps, fp32.
// Layer1 charge accumulated incrementally: c1_acc += x_chunk_t @ W1_chunk_t.
// LIF (tau=2, vth=1, hard reset) fused into GEMM epilogue.

#define BM 64
#define BN 64
#define BK 16
#define TM 4
#define TN 4

__global__ __launch_bounds__(256)
void gemm_lif(const float* __restrict__ A, int lda,
              const float* __restrict__ B, int ldb,
              const float* __restrict__ bias,
              float* __restrict__ cacc,   // nullable: layer-1 running charge
              float* __restrict__ v,
              float* __restrict__ s,
              int M, int N, int K)
{
    __shared__ float As[BK][BM + 4];   // stored transposed: As[k][m]
    __shared__ float Bs[BK][BN + 4];

    const int tid  = threadIdx.x;
    const int tx   = tid & 15;         // micro-tile col group
    const int ty   = tid >> 4;         // micro-tile row group
    const int row0 = blockIdx.y * BM;
    const int col0 = blockIdx.x * BN;

    // A-load mapping: 64 rows x 16 k, float4 along k => 256 threads
    const int am = tid >> 2;           // 0..63
    const int ak = (tid & 3) * 4;      // 0,4,8,12
    // B-load mapping: 16 k x 64 n, float4 along n => 256 threads
    const int bk = tid >> 4;           // 0..15
    const int bn = (tid & 15) * 4;     // 0..60

    float acc[TM][TN];
    #pragma unroll
    for (int i = 0; i < TM; ++i)
        #pragma unroll
        for (int j = 0; j < TN; ++j) acc[i][j] = 0.f;

    for (int k0 = 0; k0 < K; k0 += BK) {
        // A tile (always in-bounds: M%64==0, K%16==0, fp32 rows 16B-alignable)
        {
            const float4 a4 = *(const float4*)(A + (size_t)(row0 + am) * lda + (k0 + ak));
            As[ak + 0][am] = a4.x;
            As[ak + 1][am] = a4.y;
            As[ak + 2][am] = a4.z;
            As[ak + 3][am] = a4.w;
        }
        // B tile (guard cols: N=1000 tile is partial)
        {
            const int col = col0 + bn;
            const float* bp = B + (size_t)(k0 + bk) * ldb + col;
            float4 b4;
            if (col + 3 < N) {
                b4 = *(const float4*)bp;
            } else {
                b4.x = (col + 0 < N) ? bp[0] : 0.f;
                b4.y = (col + 1 < N) ? bp[1] : 0.f;
                b4.z = (col + 2 < N) ? bp[2] : 0.f;
                b4.w = 0.f;
            }
            *(float4*)&Bs[bk][bn] = b4;
        }
        __syncthreads();

        #pragma unroll
        for (int kk = 0; kk < BK; ++kk) {
            float a_frag[TM], b_frag[TN];
            #pragma unroll
            for (int i = 0; i < TM; ++i) a_frag[i] = As[kk][ty * TM + i];
            #pragma unroll
            for (int j = 0; j < TN; ++j) b_frag[j] = Bs[kk][tx * TN + j];
            #pragma unroll
            for (int i = 0; i < TM; ++i)
                #pragma unroll
                for (int j = 0; j < TN; ++j)
                    acc[i][j] += a_frag[i] * b_frag[j];
        }
        __syncthreads();
    }

    // Fused LIF epilogue: v' = (v + c)/2 ; s = v' >= 1 ; v = s ? 0 : v'
    #pragma unroll
    for (int i = 0; i < TM; ++i) {
        const int r = row0 + ty * TM + i;
        #pragma unroll
        for (int j = 0; j < TN; ++j) {
            const int c = col0 + tx * TN + j;
            if (c >= N) continue;
            const size_t idx = (size_t)r * N + c;
            float dot = acc[i][j];
            if (cacc) {                 // layer 1: accumulate prefix charge
                dot += cacc[idx];
                cacc[idx] = dot;
            }
            const float ch = dot + bias[c];
            const float vv = (v[idx] + ch) * 0.5f;
            const float sp = (vv >= 1.0f) ? 1.0f : 0.0f;
            v[idx] = (sp != 0.0f) ? 0.0f : vv;
            s[idx] = sp;
        }
    }
}

extern "C" void kernel_launch(void* const* d_in, const int* in_sizes, int n_in,
                              void* d_out, int out_size, void* d_ws, size_t ws_size,
                              hipStream_t stream) {
    const float* x  = (const float*)d_in[0];
    const float* W1 = (const float*)d_in[1];
    const float* b1 = (const float*)d_in[2];
    const float* W2 = (const float*)d_in[3];
    const float* b2 = (const float*)d_in[4];
    const float* W3 = (const float*)d_in[5];
    const float* b3 = (const float*)d_in[6];
    float* out = (float*)d_out;

    const int Bb = 1024, D = 4000, H = 2048, O = 1000, T = 10, CH = 400;
    const size_t BH = (size_t)Bb * H, BO = (size_t)Bb * O;

    float* ws = (float*)d_ws;
    float* c1 = ws;            // B*H running layer-1 charge
    float* v1 = c1 + BH;       // B*H
    float* s1 = v1 + BH;       // B*H
    float* v2 = s1 + BH;       // B*H
    float* s2 = v2 + BH;       // B*H
    float* v3 = s2 + BH;       // B*O

    // zero state (ws is poisoned 0xAA before every timed call)
    hipMemsetAsync(d_ws, 0, (5 * BH + BO) * sizeof(float), stream);

    const dim3 blk(256);
    const dim3 g1(H / BN, Bb / BM);                  // 32 x 16
    const dim3 g2(H / BN, Bb / BM);                  // 32 x 16
    const dim3 g3((O + BN - 1) / BN, Bb / BM);       // 16 x 16 (partial col tile)

    for (int t = 0; t < T; ++t) {
        // layer 1: incremental chunk GEMM (K=400) + LIF
        gemm_lif<<<g1, blk, 0, stream>>>(x + t * CH, D,
                                         W1 + (size_t)t * CH * H, H,
                                         b1, c1, v1, s1, Bb, H, CH);
        // layer 2: s1 @ W2 + LIF
        gemm_lif<<<g2, blk, 0, stream>>>(s1, H, W2, H, b2, nullptr, v2, s2, Bb, H, H);
        // layer 3: s2 @ W3 + LIF (spikes -> d_out, last step wins)
        gemm_lif<<<g3, blk, 0, stream>>>(s2, H, W3, O, b3, nullptr, v3, out, Bb, O, H);
    }
}

// Round 2
// 1461.369 us; speedup vs baseline: 2.3805x; 2.3805x over previous
//
#include <hip/hip_runtime.h>
#include <hip/hip_bf16.h>

// SNN 3-layer LIF MLP, T=10. fp32 reference.
// L1: incremental-chunk fp32 VALU GEMM (K=400/step), emits s1 as bf16.
// L2/L3: MFMA bf16 NT-GEMM with 3-way bf16 split of W (fp32-accurate):
//        W = hi + mid + lo (each bf16, residuals exact by Sterbenz),
//        A = spikes (binary -> exact in bf16). Accumulate all 3 planes in fp32 AGPRs.
// LIF (tau=2, vth=1, hard reset) fused into every epilogue.

typedef __attribute__((ext_vector_type(8))) short short8;
typedef float f32x4 __attribute__((ext_vector_type(4)));

// ---------------------------------------------------------------- L1 fp32 GEMM
#define BM 64
#define BN 64
#define BK 16
#define TM 4
#define TN 4

__global__ __launch_bounds__(256)
void gemm_lif_f32(const float* __restrict__ A, int lda,
                  const float* __restrict__ B, int ldb,
                  const float* __restrict__ bias,
                  float* __restrict__ cacc,           // layer-1 running charge
                  float* __restrict__ v,
                  __hip_bfloat16* __restrict__ s,     // spikes out (bf16)
                  int M, int N, int K)
{
    __shared__ float As[BK][BM + 4];
    __shared__ float Bs[BK][BN + 4];

    const int tid  = threadIdx.x;
    const int tx   = tid & 15;
    const int ty   = tid >> 4;
    const int row0 = blockIdx.y * BM;
    const int col0 = blockIdx.x * BN;

    const int am = tid >> 2;
    const int ak = (tid & 3) * 4;
    const int bk = tid >> 4;
    const int bn = (tid & 15) * 4;

    float acc[TM][TN];
    #pragma unroll
    for (int i = 0; i < TM; ++i)
        #pragma unroll
        for (int j = 0; j < TN; ++j) acc[i][j] = 0.f;

    for (int k0 = 0; k0 < K; k0 += BK) {
        {
            const float4 a4 = *(const float4*)(A + (size_t)(row0 + am) * lda + (k0 + ak));
            As[ak + 0][am] = a4.x;
            As[ak + 1][am] = a4.y;
            As[ak + 2][am] = a4.z;
            As[ak + 3][am] = a4.w;
        }
        {
            const float4 b4 = *(const float4*)(B + (size_t)(k0 + bk) * ldb + (col0 + bn));
            *(float4*)&Bs[bk][bn] = b4;
        }
        __syncthreads();

        #pragma unroll
        for (int kk = 0; kk < BK; ++kk) {
            float a_frag[TM], b_frag[TN];
            #pragma unroll
            for (int i = 0; i < TM; ++i) a_frag[i] = As[kk][ty * TM + i];
            #pragma unroll
            for (int j = 0; j < TN; ++j) b_frag[j] = Bs[kk][tx * TN + j];
            #pragma unroll
            for (int i = 0; i < TM; ++i)
                #pragma unroll
                for (int j = 0; j < TN; ++j)
                    acc[i][j] += a_frag[i] * b_frag[j];
        }
        __syncthreads();
    }

    #pragma unroll
    for (int i = 0; i < TM; ++i) {
        const int r = row0 + ty * TM + i;
        #pragma unroll
        for (int j = 0; j < TN; ++j) {
            const int c = col0 + tx * TN + j;
            const size_t idx = (size_t)r * N + c;
            float dot = acc[i][j] + cacc[idx];
            cacc[idx] = dot;
            const float ch = dot + bias[c];
            const float vv = (v[idx] + ch) * 0.5f;
            const float sp = (vv >= 1.0f) ? 1.0f : 0.0f;
            v[idx] = (sp != 0.0f) ? 0.0f : vv;
            s[idx] = __float2bfloat16(sp);
        }
    }
}

// ------------------------------------------------- W split+transpose (3 planes)
// In:  W [K][Nreal] fp32   Out: 3 planes, each [Npad][K] bf16 (NT layout)
__global__ __launch_bounds__(256)
void split3_t(const float* __restrict__ W, int K, int Nreal, int Npad,
              __hip_bfloat16* __restrict__ out)
{
    __shared__ float t[32][33];
    const int k0 = blockIdx.x * 32, n0 = blockIdx.y * 32;
    const int tx = threadIdx.x & 31, ty = threadIdx.x >> 5;   // 32 x 8

    #pragma unroll
    for (int i = 0; i < 4; ++i) {
        const int k = k0 + ty + i * 8;
        const int n = n0 + tx;
        t[ty + i * 8][tx] = (n < Nreal) ? W[(size_t)k * Nreal + n] : 0.f;
    }
    __syncthreads();
    const size_t plane = (size_t)Npad * K;
    #pragma unroll
    for (int i = 0; i < 4; ++i) {
        const int n = n0 + ty + i * 8;
        const int k = k0 + tx;
        const float val = t[tx][ty + i * 8];
        const __hip_bfloat16 hi = __float2bfloat16(val);
        const float r1 = val - __bfloat162float(hi);
        const __hip_bfloat16 mid = __float2bfloat16(r1);
        const float r2 = r1 - __bfloat162float(mid);
        const __hip_bfloat16 lo = __float2bfloat16(r2);
        const size_t idx = (size_t)n * K + k;
        out[idx]             = hi;
        out[plane + idx]     = mid;
        out[2 * plane + idx] = lo;
    }
}

// ------------------------------------------------------------- MFMA LIF GEMM
// C[M][Npad] = A[M][K](bf16) @ sum_p Bp[Npad][K]^T ; LIF epilogue.
__global__ __launch_bounds__(256)
void mfma_lif(const __hip_bfloat16* __restrict__ A,
              const __hip_bfloat16* __restrict__ Bp,   // 3 planes [Npad][K]
              const float* __restrict__ bias,          // [Npad]
              float* __restrict__ v,                   // [M][Npad]
              __hip_bfloat16* __restrict__ s_bf,       // nullable [M][Npad]
              float* __restrict__ s_f32,               // nullable [M][Nreal]
              int M, int K, int Npad, int Nreal)
{
    __shared__ __hip_bfloat16 As[64][40];       // +8 bf16 pad: 80B row stride
    __shared__ __hip_bfloat16 Bs[3][64][40];

    const int tid  = threadIdx.x;
    const int lane = tid & 63;
    const int w    = tid >> 6;
    const int wm   = (w >> 1) * 32;
    const int wn   = (w & 1) * 32;
    const int m0   = blockIdx.y * 64;
    const int n0   = blockIdx.x * 64;
    const size_t plane = (size_t)Npad * K;

    const int lr = tid >> 2;          // staging row 0..63
    const int ls = (tid & 3) * 8;     // staging k-offset (8 bf16 = 16 B)

    f32x4 acc[2][2] = {};

    const int lm = lane & 15;         // fragment row/col within 16
    const int lk = (lane >> 4) * 8;   // fragment k-chunk

    for (int k0 = 0; k0 < K; k0 += 32) {
        *(float4*)&As[lr][ls] =
            *(const float4*)(A + (size_t)(m0 + lr) * K + k0 + ls);
        #pragma unroll
        for (int p = 0; p < 3; ++p)
            *(float4*)&Bs[p][lr][ls] =
                *(const float4*)(Bp + p * plane + (size_t)(n0 + lr) * K + k0 + ls);
        __syncthreads();

        const short8 a0 = *(const short8*)&As[wm + lm][lk];
        const short8 a1 = *(const short8*)&As[wm + 16 + lm][lk];
        #pragma unroll
        for (int p = 0; p < 3; ++p) {
            const short8 b0 = *(const short8*)&Bs[p][wn + lm][lk];
            const short8 b1 = *(const short8*)&Bs[p][wn + 16 + lm][lk];
            acc[0][0] = __builtin_amdgcn_mfma_f32_16x16x32_bf16(a0, b0, acc[0][0], 0, 0, 0);
            acc[0][1] = __builtin_amdgcn_mfma_f32_16x16x32_bf16(a0, b1, acc[0][1], 0, 0, 0);
            acc[1][0] = __builtin_amdgcn_mfma_f32_16x16x32_bf16(a1, b0, acc[1][0], 0, 0, 0);
            acc[1][1] = __builtin_amdgcn_mfma_f32_16x16x32_bf16(a1, b1, acc[1][1], 0, 0, 0);
        }
        __syncthreads();
    }

    // Epilogue: C/D layout (16x16x32): col = lane&15, row = (lane>>4)*4 + reg
    const int rq = (lane >> 4) * 4;
    #pragma unroll
    for (int mi = 0; mi < 2; ++mi) {
        #pragma unroll
        for (int ni = 0; ni < 2; ++ni) {
            const int n = n0 + wn + ni * 16 + lm;
            const float bb = bias[n];
            #pragma unroll
            for (int r = 0; r < 4; ++r) {
                const int m = m0 + wm + mi * 16 + rq + r;
                const size_t idx = (size_t)m * Npad + n;
                const float ch = acc[mi][ni][r] + bb;
                const float vv = (v[idx] + ch) * 0.5f;
                const float sp = (vv >= 1.0f) ? 1.0f : 0.0f;
                v[idx] = (sp != 0.0f) ? 0.0f : vv;
                if (s_bf)  s_bf[idx] = __float2bfloat16(sp);
                if (s_f32 && n < Nreal) s_f32[(size_t)m * Nreal + n] = sp;
            }
        }
    }
}

// --------------------------------------------------------------------- launch
extern "C" void kernel_launch(void* const* d_in, const int* in_sizes, int n_in,
                              void* d_out, int out_size, void* d_ws, size_t ws_size,
                              hipStream_t stream) {
    const float* x  = (const float*)d_in[0];
    const float* W1 = (const float*)d_in[1];
    const float* b1 = (const float*)d_in[2];
    const float* W2 = (const float*)d_in[3];
    const float* b2 = (const float*)d_in[4];
    const float* W3 = (const float*)d_in[5];
    const float* b3 = (const float*)d_in[6];
    float* out = (float*)d_out;

    const int Bb = 1024, D = 4000, H = 2048, O = 1000, Op = 1024, T = 10, CH = 400;
    const size_t BH = (size_t)Bb * H;          // 2,097,152
    const size_t BOp = (size_t)Bb * Op;        // 1,048,576

    float* ws = (float*)d_ws;
    // zeroed region: [c1 | v1 | v2 | v3 | b3pad]
    float* c1  = ws;                    // BH
    float* v1  = c1 + BH;               // BH
    float* v2  = v1 + BH;               // BH
    float* v3  = v2 + BH;               // BOp
    float* b3p = v3 + BOp;              // 1024 (tail >=O stays 0)
    float* zend = b3p + 1024;
    // non-zeroed:
    __hip_bfloat16* s1  = (__hip_bfloat16*)zend;            // BH bf16
    __hip_bfloat16* s2  = (__hip_bfloat16*)(zend + BH / 2); // BH bf16
    __hip_bfloat16* w2s = (__hip_bfloat16*)(zend + BH);               // 3*H*H bf16
    __hip_bfloat16* w3s = w2s + (size_t)3 * H * H;                    // 3*Op*H bf16

    hipMemsetAsync(d_ws, 0, (size_t)((3 * BH + BOp + 1024)) * sizeof(float), stream);
    hipMemcpyAsync(b3p, b3, O * sizeof(float), hipMemcpyDeviceToDevice, stream);

    // Split + transpose weights into 3 bf16 planes (NT layout [Npad][K])
    split3_t<<<dim3(H / 32, H / 32), 256, 0, stream>>>(W2, H, H, H, w2s);
    split3_t<<<dim3(H / 32, Op / 32), 256, 0, stream>>>(W3, H, O, Op, w3s);

    const dim3 blk(256);
    const dim3 g1(H / BN, Bb / BM);          // L1 fp32: 32 x 16
    const dim3 g2(H / 64, Bb / 64);          // L2 mfma: 32 x 16
    const dim3 g3(Op / 64, Bb / 64);         // L3 mfma: 16 x 16

    for (int t = 0; t < T; ++t) {
        gemm_lif_f32<<<g1, blk, 0, stream>>>(x + t * CH, D,
                                             W1 + (size_t)t * CH * H, H,
                                             b1, c1, v1, s1, Bb, H, CH);
        mfma_lif<<<g2, blk, 0, stream>>>(s1, w2s, b2, v2, s2, nullptr,
                                         Bb, H, H, H);
        mfma_lif<<<g3, blk, 0, stream>>>(s2, w3s, b3p, v3, nullptr,
                                         (t == T - 1) ? out : nullptr,
                                         Bb, H, Op, O);
    }
}

// Round 3
// 1281.114 us; speedup vs baseline: 2.7155x; 1.1407x over previous
//
#include <hip/hip_runtime.h>
#include <hip/hip_bf16.h>

// SNN 3-layer LIF MLP, T=10, fp32 reference. All GEMMs on MFMA bf16 with
// exact 3-plane bf16 weight/activation splits (Sterbenz residuals).
// L1: x(3 planes) @ W1(3 planes), 6 plane-pairs, incremental K-chunks (416-padded).
// L2/L3: binary spikes (1 plane, exact) @ W(3 planes).
// Staging: global_load_lds 16B into XOR-swizzled LDS granule layout
// (slot = s*8 + ((g+s)&7), s=m>>1, g=(m&1)*4+chunk) -> 2-way-max bank access.
// XCD swizzle: blockIdx%8 -> XCD gets a contiguous N-slab so B fits per-XCD L2.

typedef __attribute__((ext_vector_type(8))) short short8;
typedef float f32x4 __attribute__((ext_vector_type(4)));

#ifndef __has_builtin
#define __has_builtin(x) 0
#endif
#if __has_builtin(__builtin_amdgcn_global_load_lds)
#define HAS_GLLDS 1
#else
#define HAS_GLLDS 0
#endif

// ------------------------------------------------------------- unified MFMA+LIF
// MODE 0: 1 A-plane x 3 B-planes (pairs (0,0)(0,1)(0,2))   [L2, L3]
// MODE 1: 3 A-planes x 3 B-planes, 6 pairs                 [L1]
template<int MODE>
__global__ __launch_bounds__(256)
void mfma_lif(const __hip_bfloat16* __restrict__ A, size_t aStride, int lda,
              const __hip_bfloat16* __restrict__ B, size_t bStride, int ldb,
              int K,
              const float* __restrict__ bias,
              float* __restrict__ cacc,            // nullable (L1 running charge)
              float* __restrict__ v,
              __hip_bfloat16* __restrict__ sbf,    // nullable spikes (bf16)
              float* __restrict__ sf32,            // nullable spikes (f32, n<Nreal)
              int Npad, int Nreal, int ls)         // ls = log2(n_tiles/8)
{
    constexpr int NA = MODE ? 3 : 1;
    constexpr int NB = 3;
    constexpr int NP = MODE ? 6 : 3;
    constexpr int PA1[6] = {0,0,1,0,2,1}, PB1[6] = {0,1,0,2,0,1};
    constexpr int PA0[3] = {0,0,0},       PB0[3] = {0,1,2};

    __shared__ char tiles[(NA + NB) * 4096];   // each tile: 64 rows x 32 bf16

    const int tid = threadIdx.x;
    const int b   = blockIdx.x;
    const int xcd = b & 7, ii = b >> 3;
    const int ntp = 1 << ls;
    const int n_tile = xcd * ntp + (ii & (ntp - 1));
    const int m_tile = ii >> ls;
    const int m0 = m_tile * 64, n0 = n_tile * 64;

    // staging decode: this thread fills granule-slot `tid` of each tile
    const int ss = tid >> 3;
    const int gg = ((tid & 7) - ss) & 7;
    const int sm = 2 * ss + (gg >> 2);        // source row in tile
    const int sc = gg & 3;                    // source 16B-chunk in row
    char* wbase = tiles + (tid & ~63) * 16;   // wave-uniform dest base

    const __hip_bfloat16* aSrc = A + (size_t)(m0 + sm) * lda + sc * 8;
    const __hip_bfloat16* bSrc = B + (size_t)(n0 + sm) * ldb + sc * 8;

    const int lane = tid & 63;
    const int w    = tid >> 6;
    const int wm   = (w >> 1) * 32, wn = (w & 1) * 32;
    const int lm   = lane & 15, ck = lane >> 4;

    f32x4 acc[2][2] = {};

    for (int k0 = 0; k0 < K; k0 += 32) {
        #pragma unroll
        for (int p = 0; p < NA; ++p) {
            const __hip_bfloat16* gp = aSrc + p * aStride + k0;
#if HAS_GLLDS
            __builtin_amdgcn_global_load_lds(
                (const __attribute__((address_space(1))) void*)gp,
                (__attribute__((address_space(3))) void*)(wbase + p * 4096), 16, 0, 0);
#else
            *(float4*)(tiles + p * 4096 + tid * 16) = *(const float4*)gp;
#endif
        }
        #pragma unroll
        for (int q = 0; q < NB; ++q) {
            const __hip_bfloat16* gq = bSrc + q * bStride + k0;
#if HAS_GLLDS
            __builtin_amdgcn_global_load_lds(
                (const __attribute__((address_space(1))) void*)gq,
                (__attribute__((address_space(3))) void*)(wbase + (NA + q) * 4096), 16, 0, 0);
#else
            *(float4*)(tiles + (NA + q) * 4096 + tid * 16) = *(const float4*)gq;
#endif
        }
        __syncthreads();   // drains vmcnt (global_load_lds) + lgkm

        // fragment reads from swizzled layout
        short8 aF[NA][2], bF[NB][2];
        #pragma unroll
        for (int p = 0; p < NA; ++p) {
            #pragma unroll
            for (int i = 0; i < 2; ++i) {
                const int m = wm + i * 16 + lm;
                const int s2 = m >> 1;
                const int slot = s2 * 8 + ((((m & 1) << 2) + ck + s2) & 7);
                aF[p][i] = *(const short8*)(tiles + p * 4096 + slot * 16);
            }
        }
        #pragma unroll
        for (int q = 0; q < NB; ++q) {
            #pragma unroll
            for (int j = 0; j < 2; ++j) {
                const int n = wn + j * 16 + lm;
                const int s2 = n >> 1;
                const int slot = s2 * 8 + ((((n & 1) << 2) + ck + s2) & 7);
                bF[q][j] = *(const short8*)(tiles + (NA + q) * 4096 + slot * 16);
            }
        }

        #pragma unroll
        for (int pp = 0; pp < NP; ++pp) {
            const int pa = MODE ? PA1[pp] : PA0[pp];
            const int pb = MODE ? PB1[pp] : PB0[pp];
            #pragma unroll
            for (int i = 0; i < 2; ++i)
                #pragma unroll
                for (int j = 0; j < 2; ++j)
                    acc[i][j] = __builtin_amdgcn_mfma_f32_16x16x32_bf16(
                        aF[pa][i], bF[pb][j], acc[i][j], 0, 0, 0);
        }
        __syncthreads();
    }

    // LIF epilogue. C/D layout: col = lane&15, row = (lane>>4)*4 + reg
    const int rq = (lane >> 4) * 4;
    #pragma unroll
    for (int mi = 0; mi < 2; ++mi) {
        #pragma unroll
        for (int ni = 0; ni < 2; ++ni) {
            const int n = n0 + wn + ni * 16 + lm;
            const float bb = bias[n];
            #pragma unroll
            for (int r = 0; r < 4; ++r) {
                const int m = m0 + wm + mi * 16 + rq + r;
                const size_t idx = (size_t)m * Npad + n;
                float dot = acc[mi][ni][r];
                if (cacc) { dot += cacc[idx]; cacc[idx] = dot; }
                const float ch = dot + bb;
                const float vv = (v[idx] + ch) * 0.5f;
                const float sp = (vv >= 1.0f) ? 1.0f : 0.0f;
                v[idx] = (sp != 0.0f) ? 0.0f : vv;
                if (sbf)  sbf[idx] = __float2bfloat16(sp);
                if (sf32 && n < Nreal) sf32[(size_t)m * Nreal + n] = sp;
            }
        }
    }
}

// ---------------------------------------------------------------- weight splits
__device__ __forceinline__ void bf16split3(float val, __hip_bfloat16& hi,
                                           __hip_bfloat16& mid, __hip_bfloat16& lo) {
    hi = __float2bfloat16(val);
    const float r1 = val - __bfloat162float(hi);
    mid = __float2bfloat16(r1);
    const float r2 = r1 - __bfloat162float(mid);
    lo = __float2bfloat16(r2);
}

// W [K][Nreal] fp32 -> 3 planes [Npad][K] bf16 (NT)
__global__ __launch_bounds__(256)
void split3_t(const float* __restrict__ W, int K, int Nreal, int Npad,
              __hip_bfloat16* __restrict__ out)
{
    __shared__ float t[32][33];
    const int k0 = blockIdx.x * 32, n0 = blockIdx.y * 32;
    const int tx = threadIdx.x & 31, ty = threadIdx.x >> 5;
    #pragma unroll
    for (int i = 0; i < 4; ++i) {
        const int k = k0 + ty + i * 8, n = n0 + tx;
        t[ty + i * 8][tx] = (n < Nreal) ? W[(size_t)k * Nreal + n] : 0.f;
    }
    __syncthreads();
    const size_t plane = (size_t)Npad * K;
    #pragma unroll
    for (int i = 0; i < 4; ++i) {
        const int n = n0 + ty + i * 8, k = k0 + tx;
        __hip_bfloat16 hi, mid, lo;
        bf16split3(t[tx][ty + i * 8], hi, mid, lo);
        const size_t idx = (size_t)n * K + k;
        out[idx] = hi; out[plane + idx] = mid; out[2 * plane + idx] = lo;
    }
}

// W1 [4000][2048] -> 3 planes [2048][4160] bf16 (NT, per-chunk K padded 400->416)
__global__ __launch_bounds__(256)
void split3_w1(const float* __restrict__ W1, __hip_bfloat16* __restrict__ out)
{
    __shared__ float t[32][33];
    const int kk0 = blockIdx.x * 32, n0 = blockIdx.y * 32;
    const int tx = threadIdx.x & 31, ty = threadIdx.x >> 5;
    #pragma unroll
    for (int i = 0; i < 4; ++i) {
        const int kk = kk0 + ty + i * 8;
        const int tt = kk / 416, j = kk - tt * 416;
        t[ty + i * 8][tx] = (j < 400) ? W1[(size_t)(tt * 400 + j) * 2048 + (n0 + tx)] : 0.f;
    }
    __syncthreads();
    const size_t plane = (size_t)2048 * 4160;
    #pragma unroll
    for (int i = 0; i < 4; ++i) {
        const int n = n0 + ty + i * 8, kk = kk0 + tx;
        __hip_bfloat16 hi, mid, lo;
        bf16split3(t[tx][ty + i * 8], hi, mid, lo);
        const size_t idx = (size_t)n * 4160 + kk;
        out[idx] = hi; out[plane + idx] = mid; out[2 * plane + idx] = lo;
    }
}

// x [1024][4000] -> 3 planes [1024][4160] bf16 (per-chunk K padded)
__global__ __launch_bounds__(256)
void splitx(const float* __restrict__ x, __hip_bfloat16* __restrict__ out)
{
    const int id = blockIdx.x * 256 + threadIdx.x;
    if (id >= 1024 * 4160) return;
    const int m = id / 4160, kk = id - m * 4160;
    const int tt = kk / 416, j = kk - tt * 416;
    const float val = (j < 400) ? x[(size_t)m * 4000 + tt * 400 + j] : 0.f;
    const size_t PS = (size_t)1024 * 4160;
    __hip_bfloat16 hi, mid, lo;
    bf16split3(val, hi, mid, lo);
    out[id] = hi; out[PS + id] = mid; out[2 * PS + id] = lo;
}

// -------------------------------------------------- fallback L1 fp32 VALU GEMM
#define BM 64
#define BN 64
#define BK 16
#define TM 4
#define TN 4
__global__ __launch_bounds__(256)
void gemm_lif_f32(const float* __restrict__ A, int lda,
                  const float* __restrict__ B, int ldb,
                  const float* __restrict__ bias,
                  float* __restrict__ cacc, float* __restrict__ v,
                  __hip_bfloat16* __restrict__ s, int M, int N, int K)
{
    __shared__ float As[BK][BM + 4];
    __shared__ float Bs[BK][BN + 4];
    const int tid = threadIdx.x;
    const int tx = tid & 15, ty = tid >> 4;
    const int row0 = blockIdx.y * BM, col0 = blockIdx.x * BN;
    const int am = tid >> 2, ak = (tid & 3) * 4;
    const int bk = tid >> 4, bn = (tid & 15) * 4;
    float acc[TM][TN];
    #pragma unroll
    for (int i = 0; i < TM; ++i)
        #pragma unroll
        for (int j = 0; j < TN; ++j) acc[i][j] = 0.f;
    for (int k0 = 0; k0 < K; k0 += BK) {
        const float4 a4 = *(const float4*)(A + (size_t)(row0 + am) * lda + (k0 + ak));
        As[ak + 0][am] = a4.x; As[ak + 1][am] = a4.y;
        As[ak + 2][am] = a4.z; As[ak + 3][am] = a4.w;
        *(float4*)&Bs[bk][bn] = *(const float4*)(B + (size_t)(k0 + bk) * ldb + (col0 + bn));
        __syncthreads();
        #pragma unroll
        for (int kk = 0; kk < BK; ++kk) {
            float a_frag[TM], b_frag[TN];
            #pragma unroll
            for (int i = 0; i < TM; ++i) a_frag[i] = As[kk][ty * TM + i];
            #pragma unroll
            for (int j = 0; j < TN; ++j) b_frag[j] = Bs[kk][tx * TN + j];
            #pragma unroll
            for (int i = 0; i < TM; ++i)
                #pragma unroll
                for (int j = 0; j < TN; ++j) acc[i][j] += a_frag[i] * b_frag[j];
        }
        __syncthreads();
    }
    #pragma unroll
    for (int i = 0; i < TM; ++i) {
        const int r = row0 + ty * TM + i;
        #pragma unroll
        for (int j = 0; j < TN; ++j) {
            const int c = col0 + tx * TN + j;
            const size_t idx = (size_t)r * N + c;
            float dot = acc[i][j] + cacc[idx];
            cacc[idx] = dot;
            const float ch = dot + bias[c];
            const float vv = (v[idx] + ch) * 0.5f;
            const float sp = (vv >= 1.0f) ? 1.0f : 0.0f;
            v[idx] = (sp != 0.0f) ? 0.0f : vv;
            s[idx] = __float2bfloat16(sp);
        }
    }
}

// --------------------------------------------------------------------- launch
extern "C" void kernel_launch(void* const* d_in, const int* in_sizes, int n_in,
                              void* d_out, int out_size, void* d_ws, size_t ws_size,
                              hipStream_t stream) {
    const float* x  = (const float*)d_in[0];
    const float* W1 = (const float*)d_in[1];
    const float* b1 = (const float*)d_in[2];
    const float* W2 = (const float*)d_in[3];
    const float* b2 = (const float*)d_in[4];
    const float* W3 = (const float*)d_in[5];
    const float* b3 = (const float*)d_in[6];
    float* out = (float*)d_out;

    const int Bb = 1024, D = 4000, H = 2048, O = 1000, Op = 1024, T = 10, CH = 400;
    const int KP = 4160, CHP = 416;   // padded K for L1 chunks
    const size_t BH = (size_t)Bb * H, BOp = (size_t)Bb * Op;

    float* ws = (float*)d_ws;
    float* c1  = ws;                       // BH
    float* v1  = c1 + BH;                  // BH
    float* v2  = v1 + BH;                  // BH
    float* v3  = v2 + BH;                  // BOp
    float* b3p = v3 + BOp;                 // 1024
    float* zend = b3p + 1024;
    __hip_bfloat16* s1  = (__hip_bfloat16*)zend;                 // BH
    __hip_bfloat16* s2  = s1 + BH;                               // BH
    __hip_bfloat16* w2s = s2 + BH;                               // 3*H*H
    __hip_bfloat16* w3s = w2s + (size_t)3 * H * H;               // 3*Op*H
    __hip_bfloat16* w1s = w3s + (size_t)3 * Op * H;              // 3*H*KP
    __hip_bfloat16* xs  = w1s + (size_t)3 * H * KP;              // 3*Bb*KP
    const size_t zero_bytes = ((size_t)3 * BH + BOp + 1024) * sizeof(float);
    const size_t need_big = zero_bytes +
        (2 * BH + (size_t)3 * H * H + (size_t)3 * Op * H +
         (size_t)3 * H * KP + (size_t)3 * Bb * KP) * sizeof(__hip_bfloat16);
    const bool bigws = ws_size >= need_big;

    hipMemsetAsync(d_ws, 0, zero_bytes, stream);
    hipMemcpyAsync(b3p, b3, O * sizeof(float), hipMemcpyDeviceToDevice, stream);

    split3_t<<<dim3(H / 32, H / 32), 256, 0, stream>>>(W2, H, H, H, w2s);
    split3_t<<<dim3(H / 32, Op / 32), 256, 0, stream>>>(W3, H, O, Op, w3s);
    if (bigws) {
        split3_w1<<<dim3(KP / 32, H / 32), 256, 0, stream>>>(W1, w1s);
        splitx<<<dim3((Bb * KP + 255) / 256), 256, 0, stream>>>(x, xs);
    }

    const size_t PSx = (size_t)Bb * KP;    // x plane stride
    const size_t PSw1 = (size_t)H * KP;    // w1 plane stride
    const dim3 blk(256);
    const dim3 g1f(H / BN, Bb / BM);

    for (int t = 0; t < T; ++t) {
        if (bigws) {
            mfma_lif<1><<<512, blk, 0, stream>>>(
                xs + t * CHP, PSx, KP, w1s + t * CHP, PSw1, KP, CHP,
                b1, c1, v1, s1, nullptr, H, H, 2);
        } else {
            gemm_lif_f32<<<g1f, blk, 0, stream>>>(x + t * CH, D,
                                                  W1 + (size_t)t * CH * H, H,
                                                  b1, c1, v1, s1, Bb, H, CH);
        }
        mfma_lif<0><<<512, blk, 0, stream>>>(
            s1, 0, H, w2s, (size_t)H * H, H, H,
            b2, nullptr, v2, s2, nullptr, H, H, 2);
        mfma_lif<0><<<256, blk, 0, stream>>>(
            s2, 0, H, w3s, (size_t)Op * H, H, H,
            b3p, nullptr, v3, nullptr, (t == T - 1) ? out : nullptr, Op, O, 1);
    }
}